// Round 9
// baseline (44.158 us; speedup 1.0000x reference)
//
#include <hip/hip_runtime.h>
#include <hip/hip_bf16.h>

#define NB 16      // batch
#define TT 1024    // Tq == Tk
#define NH 4       // heads
#define HD 6       // head dim
#define DM 24      // model dim

// (1/sqrt(6)) * log2(e) -- applied to Q after projection (exp2-domain scores)
#define QSC 0.5889785f
// fixed conservative bias in log2 domain; all key-split blocks use the SAME
// bias, so partials (l, acc) combine by plain addition; softmax exact.
#define MBIAS 32.0f

typedef float v2f __attribute__((ext_vector_type(2)));

// pack two f32 into one u32 of bf16 (lo=a, hi=b), round-to-nearest-even
__device__ __forceinline__ unsigned pack2bf(float a, float b) {
  unsigned ua = __float_as_uint(a), ub = __float_as_uint(b);
  ua += 0x7fffu + ((ua >> 16) & 1u);
  ub += 0x7fffu + ((ub >> 16) & 1u);
  return (ua >> 16) | (ub & 0xffff0000u);
}

// unpack u32 (bf16 lo,hi) -> v2f {lo,hi}
#define UNP(u, dst)                                  \
  {                                                  \
    dst.x = __uint_as_float((u) << 16);              \
    dst.y = __uint_as_float((u) & 0xffff0000u);      \
  }

// ---------------- kernel 1: fused QKV projection + attention ----------------
// R8 post-mortem: DS-pipe instruction throughput is the wall (6 ds_read_b128
// per pair-iteration, ~6.1K/CU ~ 26us). Fix: K/V staged in LDS as bf16 pairs
// -> slot = 12 u32 = 48B = 3 ds_read_b128/iter (DS work /2); unpack is VALU
// (different pipe, co-issues). Q stays f32; K/V rounded RNE (0.2% rel).
// Grid: 64 bh x 8 qtiles x 2 ksplits = 1024 blocks (4/CU). Block: 256 thr =
// 64 query-groups (NQ=2) x 4 lane-splits. LDS: 256 pair-slots x 48 B = 12 KB;
// broadcast addrs for s=0..3 at u32-offset 12s -> banks {0,12,24,4},
// disjoint b128 spans -> conflict-free.
#define QB 128
#define SPLIT 4
#define NQ 2
#define KSPLIT 2
#define KPB (TT / KSPLIT)    // 512 keys per block
#define PAIRS (KPB / 2)      // 256 pairs per block
#define PPS (PAIRS / SPLIT)  // 64 iterations per thread
#define SLOTU 12             // u32 per slot

__global__ __launch_bounds__(256, 4) void fused_attn_kernel(
    const float* __restrict__ X, const float* __restrict__ Xen,
    const float* __restrict__ Wq, const float* __restrict__ Wk,
    const float* __restrict__ Wv, float* __restrict__ P) {
  __shared__ __align__(16) unsigned KVu[PAIRS * SLOTU];  // 12288 B

  const int ks = blockIdx.x & 1;
  const int tile = (blockIdx.x >> 1) & 7;
  const int bh = blockIdx.x >> 4;
  const int b = bh >> 2, h = bh & 3;
  const int t = threadIdx.x;
  const int s = t & 3;   // lane key-split
  const int g = t >> 2;  // query group 0..63
  const int q0 = tile * QB + g * NQ;

  // uniform weight slices -> scalar loads (SGPRs), no LDS
  const float* __restrict__ wqh = Wq + h * HD * DM;
  const float* __restrict__ wkh = Wk + h * HD * DM;
  const float* __restrict__ wvh = Wv + h * HD * DM;

  // packed dot of one 24-float row (6 float4, static-indexed) with a uniform
  // weight row: 12 v_pk_fma_f32 (VGPR pair x SGPR pair) + fold.
  auto dot24 = [](const float4* r, const float* __restrict__ w) -> float {
    v2f a = {0.f, 0.f};
#pragma unroll
    for (int i = 0; i < 6; ++i) {
      v2f xp, wp;
      xp.x = r[i].x; xp.y = r[i].y;
      wp.x = w[4 * i + 0]; wp.y = w[4 * i + 1];
      a = __builtin_elementwise_fma(xp, wp, a);
      xp.x = r[i].z; xp.y = r[i].w;
      wp.x = w[4 * i + 2]; wp.y = w[4 * i + 3];
      a = __builtin_elementwise_fma(xp, wp, a);
    }
    return a.x + a.y;
  };

  // ---- phase 1: K/V for keys 2t, 2t+1 -> bf16 LDS slot (dim-interleaved)
  {
    const float4* __restrict__ xe4 =
        (const float4*)(Xen + ((size_t)b * TT + ks * KPB + 2 * t) * DM);
    float4 xe[12];
#pragma unroll
    for (int i = 0; i < 12; ++i) xe[i] = xe4[i];  // row A: 0..5, row B: 6..11
    unsigned su[SLOTU];
#pragma unroll
    for (int d = 0; d < HD; ++d) {
      const float kA = dot24(xe + 0, wkh + d * DM);
      const float kB = dot24(xe + 6, wkh + d * DM);
      const float vA = dot24(xe + 0, wvh + d * DM);
      const float vB = dot24(xe + 6, wvh + d * DM);
      su[d] = pack2bf(kA, kB);
      su[6 + d] = pack2bf(vA, vB);
    }
    uint4* __restrict__ slot = (uint4*)&KVu[t * SLOTU];
    slot[0] = make_uint4(su[0], su[1], su[2], su[3]);
    slot[1] = make_uint4(su[4], su[5], su[6], su[7]);
    slot[2] = make_uint4(su[8], su[9], su[10], su[11]);
  }

  // ---- phase 2: this thread's 2 Q rows, f32 (redundant across the 4 s-lanes)
  v2f qd[NQ][HD];
  {
    const float4* __restrict__ xq4 =
        (const float4*)(X + ((size_t)b * TT + q0) * DM);
    float4 xq[12];
#pragma unroll
    for (int i = 0; i < 12; ++i) xq[i] = xq4[i];
#pragma unroll
    for (int d = 0; d < HD; ++d) {
      const float qA = dot24(xq + 0, wqh + d * DM) * QSC;
      const float qB = dot24(xq + 6, wqh + d * DM) * QSC;
      qd[0][d].x = qA; qd[0][d].y = qA;
      qd[1][d].x = qB; qd[1][d].y = qB;
    }
  }

  __syncthreads();  // KVu ready

  v2f l2[NQ];
  v2f acc[NQ][HD];
#pragma unroll
  for (int j = 0; j < NQ; ++j) {
    l2[j].x = 0.f; l2[j].y = 0.f;
#pragma unroll
    for (int d = 0; d < HD; ++d) { acc[j][d].x = 0.f; acc[j][d].y = 0.f; }
  }

  auto compute = [&](uint4 r0, uint4 r1, uint4 r2) {
    v2f kk[HD], vv[HD];
    UNP(r0.x, kk[0]) UNP(r0.y, kk[1]) UNP(r0.z, kk[2]) UNP(r0.w, kk[3])
    UNP(r1.x, kk[4]) UNP(r1.y, kk[5])
    UNP(r1.z, vv[0]) UNP(r1.w, vv[1])
    UNP(r2.x, vv[2]) UNP(r2.y, vv[3]) UNP(r2.z, vv[4]) UNP(r2.w, vv[5])
#pragma unroll
    for (int j = 0; j < NQ; ++j) {
      v2f t2 = {-MBIAS, -MBIAS};
#pragma unroll
      for (int d = 0; d < HD; ++d)
        t2 = __builtin_elementwise_fma(qd[j][d], kk[d], t2);
      v2f p2;
      p2.x = __builtin_amdgcn_exp2f(t2.x);
      p2.y = __builtin_amdgcn_exp2f(t2.y);
      l2[j] += p2;
#pragma unroll
      for (int d = 0; d < HD; ++d)
        acc[j][d] = __builtin_elementwise_fma(p2, vv[d], acc[j][d]);
    }
  };

  // software pipeline: prefetch pair i+1 (this lane's next slot: +4 slots)
  const uint4* __restrict__ p4 = (const uint4*)&KVu[s * SLOTU];
  uint4 A = p4[0], B = p4[1], C = p4[2];
  for (int i = 0; i < PPS - 1; ++i) {
    const uint4* __restrict__ n4 = p4 + SPLIT * (SLOTU / 4);
    uint4 nA = n4[0], nB = n4[1], nC = n4[2];
    compute(A, B, C);
    A = nA; B = nB; C = nC;
    p4 = n4;
  }
  compute(A, B, C);

  // reduce across the 4 lane-splits, write unnormalized partials
#pragma unroll
  for (int j = 0; j < NQ; ++j) {
    float l = l2[j].x + l2[j].y;
    float a0 = acc[j][0].x + acc[j][0].y;
    float a1 = acc[j][1].x + acc[j][1].y;
    float a2 = acc[j][2].x + acc[j][2].y;
    float a3 = acc[j][3].x + acc[j][3].y;
    float a4 = acc[j][4].x + acc[j][4].y;
    float a5 = acc[j][5].x + acc[j][5].y;
#define RED(v) v += __shfl_xor(v, 1); v += __shfl_xor(v, 2);
    RED(l) RED(a0) RED(a1) RED(a2) RED(a3) RED(a4) RED(a5)
#undef RED
    if (s == 0) {
      float* __restrict__ Pr =
          P + (((size_t)(bh * KSPLIT + ks)) * TT + (q0 + j)) * 8;
      ((float4*)Pr)[0] = make_float4(l, a0, a1, a2);
      ((float4*)Pr)[1] = make_float4(a3, a4, a5, 0.f);
    }
  }
}

// ---------- kernel 2: combine partials + output projection (as R6-R8) ------
__global__ __launch_bounds__(256, 4) void combine_outproj_kernel(
    const float* __restrict__ P, const float* __restrict__ Wo,
    float* __restrict__ out) {
  __shared__ float w[DM * DM];
  __shared__ float o[32][25];
  for (int i = threadIdx.x; i < DM * DM; i += 256) w[i] = Wo[i];
  const int r0 = blockIdx.x * 32;
  {
    const int unit = threadIdx.x >> 1, e = threadIdx.x & 1;
    const int rl = unit >> 2, h = unit & 3;
    const int r = r0 + rl, b = r >> 10, t = r & (TT - 1);
    const int bh = b * NH + h;
    const float4* __restrict__ pp =
        (const float4*)(P + (((size_t)(bh * KSPLIT + e)) * TT + t) * 8);
    float4 x0 = pp[0], x1 = pp[1];
    float l = x0.x, a0 = x0.y, a1 = x0.z, a2 = x0.w;
    float a3 = x1.x, a4 = x1.y, a5 = x1.z;
    l += __shfl_xor(l, 1);
    a0 += __shfl_xor(a0, 1);
    a1 += __shfl_xor(a1, 1);
    a2 += __shfl_xor(a2, 1);
    a3 += __shfl_xor(a3, 1);
    a4 += __shfl_xor(a4, 1);
    a5 += __shfl_xor(a5, 1);
    if (e == 0) {
      const float inv = 1.f / l;
      o[rl][h * HD + 0] = a0 * inv;
      o[rl][h * HD + 1] = a1 * inv;
      o[rl][h * HD + 2] = a2 * inv;
      o[rl][h * HD + 3] = a3 * inv;
      o[rl][h * HD + 4] = a4 * inv;
      o[rl][h * HD + 5] = a5 * inv;
    }
  }
  __syncthreads();
  const int rl = threadIdx.x >> 3, u = threadIdx.x & 7;
  const int r = r0 + rl;
  float x[DM];
#pragma unroll
  for (int c = 0; c < DM; ++c) x[c] = o[rl][c];
#pragma unroll
  for (int jj = 0; jj < 3; ++jj) {
    const int j = u * 3 + jj;
    float a = 0.f;
#pragma unroll
    for (int c = 0; c < DM; ++c) a = fmaf(x[c], w[j * DM + c], a);
    out[(size_t)r * DM + j] = a;
  }
}

// ---------- launch ----------
extern "C" void kernel_launch(void* const* d_in, const int* in_sizes, int n_in,
                              void* d_out, int out_size, void* d_ws, size_t ws_size,
                              hipStream_t stream) {
  const float* X = (const float*)d_in[0];
  const float* Xen = (const float*)d_in[1];
  // d_in[2] = I_m : dead in the reference (masked_fill result discarded)
  const float* Wq = (const float*)d_in[3];
  const float* Wk = (const float*)d_in[4];
  const float* Wv = (const float*)d_in[5];
  const float* Wo = (const float*)d_in[6];

  float* P = (float*)d_ws;  // [64 bh][2 ks][1024 q][8] = 4 MB

  fused_attn_kernel<<<NB * NH * (TT / QB) * KSPLIT, 256, 0, stream>>>(
      X, Xen, Wq, Wk, Wv, P);
  combine_outproj_kernel<<<NB * TT / 32, 256, 0, stream>>>(P, Wo,
                                                           (float*)d_out);
}

// Round 10
// 32.754 us; speedup vs baseline: 1.3482x; 1.3482x over previous
//
#include <hip/hip_runtime.h>
#include <hip/hip_bf16.h>

#define NB 16      // batch
#define TT 1024    // Tq == Tk
#define NH 4       // heads
#define HD 6       // head dim
#define DM 24      // model dim

// (1/sqrt(6)) * log2(e) -- folded into Q so scores are in exp2 domain
#define QSC 0.5889785f
// fixed conservative bias (log2 domain); softmax invariant; p <= 1, no overflow
#define MBIAS 32.0f

typedef float v2f __attribute__((ext_vector_type(2)));
typedef short bf16x8 __attribute__((ext_vector_type(8)));   // MFMA A/B frag
typedef float f32x4 __attribute__((ext_vector_type(4)));    // MFMA C/D frag

__device__ __forceinline__ unsigned cvt_pk_bf16(float lo, float hi) {
  unsigned r;
  asm("v_cvt_pk_bf16_f32 %0, %1, %2" : "=v"(r) : "v"(lo), "v"(hi));
  return r;
}

__device__ __forceinline__ bf16x8 as_bf16x8(uint4 u) {
  union { uint4 u; bf16x8 b; } c;
  c.u = u;
  return c.b;
}

// packed dot of one 24-float row (6 float4, static-indexed) with a uniform
// weight row (SGPR via s_load -- proven R8 pattern).
__device__ __forceinline__ float dot24(const float4* r,
                                       const float* __restrict__ w) {
  v2f a = {0.f, 0.f};
#pragma unroll
  for (int i = 0; i < 6; ++i) {
    v2f xp, wp;
    xp.x = r[i].x; xp.y = r[i].y;
    wp.x = w[4 * i + 0]; wp.y = w[4 * i + 1];
    a = __builtin_elementwise_fma(xp, wp, a);
    xp.x = r[i].z; xp.y = r[i].w;
    wp.x = w[4 * i + 2]; wp.y = w[4 * i + 3];
    a = __builtin_elementwise_fma(xp, wp, a);
  }
  return a.x + a.y;
}

// ---------- kernel 1: K/V projection -> global bf16 fragments ----------
// Kg[bh][key] = uint4 of 8 bf16 (k0..k5, 0, 0)  -- MFMA A-row image.
// Vtg[bh][d][m] = u32 pair (V[2m][d], V[2m+1][d]) bf16; row 6 = 1.0 (for l).
// Projected ONCE per bh (vs x8-redundant per-block staging in R7-R9).
__global__ __launch_bounds__(256, 4) void kvproj_kernel(
    const float* __restrict__ Xen, const float* __restrict__ Wk,
    const float* __restrict__ Wv, uint4* __restrict__ Kg,
    unsigned* __restrict__ Vtg) {
  const int pp = blockIdx.x * 256 + threadIdx.x;  // pair index, [0, 64*512)
  const int bh = pp >> 9;                         // uniform per block
  const int tt = pp & 511;
  const int b = bh >> 2, h = bh & 3;
  const float* __restrict__ wkh = Wk + h * HD * DM;
  const float* __restrict__ wvh = Wv + h * HD * DM;
  const int key = 2 * tt;
  const float4* __restrict__ xa =
      (const float4*)(Xen + ((size_t)b * TT + key) * DM);
  float4 xr[12];
#pragma unroll
  for (int i = 0; i < 12; ++i) xr[i] = xa[i];  // rows key, key+1
  float kA[HD], kB[HD], vA[HD], vB[HD];
#pragma unroll
  for (int d = 0; d < HD; ++d) {
    kA[d] = dot24(xr + 0, wkh + d * DM);
    kB[d] = dot24(xr + 6, wkh + d * DM);
    vA[d] = dot24(xr + 0, wvh + d * DM);
    vB[d] = dot24(xr + 6, wvh + d * DM);
  }
  Kg[(size_t)bh * TT + key] =
      make_uint4(cvt_pk_bf16(kA[0], kA[1]), cvt_pk_bf16(kA[2], kA[3]),
                 cvt_pk_bf16(kA[4], kA[5]), 0u);
  Kg[(size_t)bh * TT + key + 1] =
      make_uint4(cvt_pk_bf16(kB[0], kB[1]), cvt_pk_bf16(kB[2], kB[3]),
                 cvt_pk_bf16(kB[4], kB[5]), 0u);
  unsigned* __restrict__ vrow = Vtg + (size_t)bh * (7 * 512);
#pragma unroll
  for (int d = 0; d < HD; ++d) vrow[d * 512 + tt] = cvt_pk_bf16(vA[d], vB[d]);
  vrow[6 * 512 + tt] = 0x3F803F80u;  // ones row -> l = P . 1 via MFMA
}

// ---------- kernel 2: MFMA attention ----------
// Per wave: 16 queries x 1024 keys. Per iteration (32 keys):
//   S^T = mfma(A=K-tile, B=Q-frag, C=-MBIAS)  x2  (d=6 padded in K=32;
//       Q-frag zero for k>=8 so A's broadcast-garbage contributes 0)
//   p = exp2(S^T regs); cvt_pk -> bf16; C-layout -> B-layout via per-wave
//       LDS scratch (2x ds_write_b64 + 1x ds_read_b128; same-wave, in-order
//       DS pipe -> no barrier);
//   O^T += mfma(A=V^T-tile, B=P^T-frag, O)   (V^T row6=1 accumulates l)
// No __syncthreads anywhere. A-frags read from L2-resident global (Kg/Vtg).
__global__ __launch_bounds__(256, 4) void attn_mfma_kernel(
    const float* __restrict__ X, const float* __restrict__ Wq,
    const uint4* __restrict__ Kg, const unsigned* __restrict__ Vtg,
    float* __restrict__ Om) {
  __shared__ unsigned Ps[4][320];  // per-wave [16 q][20 u32] (80B rows: 2-way banks)

  const int slab = blockIdx.x & 15;  // 16 slabs of 64 queries
  const int bh = blockIdx.x >> 4;
  const int b = bh >> 2, h = bh & 3;
  const int tid = threadIdx.x;
  const int w = tid >> 6;
  const int lane = tid & 63;
  const int lg = lane >> 4;    // lane group 0..3
  const int lq = lane & 15;    // query (B ops / C cols) or key-row (A ops)
  const int q = slab * 64 + w * 16 + lq;

  // ---- Q projection -> B-frag (lanes with lg==0 real, others MUST be zero)
  const float* __restrict__ wqh = Wq + h * HD * DM;
  uint4 uq;
  {
    const float4* __restrict__ xq =
        (const float4*)(X + ((size_t)b * TT + q) * DM);
    float4 xr[6];
#pragma unroll
    for (int i = 0; i < 6; ++i) xr[i] = xq[i];
    float qv[HD];
#pragma unroll
    for (int d = 0; d < HD; ++d) qv[d] = dot24(xr, wqh + d * DM) * QSC;
    uq = make_uint4(cvt_pk_bf16(qv[0], qv[1]), cvt_pk_bf16(qv[2], qv[3]),
                    cvt_pk_bf16(qv[4], qv[5]), 0u);
    if (lg != 0) uq = make_uint4(0u, 0u, 0u, 0u);
  }
  const bf16x8 qfrag = as_bf16x8(uq);

  f32x4 cmb;
  cmb[0] = -MBIAS; cmb[1] = -MBIAS; cmb[2] = -MBIAS; cmb[3] = -MBIAS;
  f32x4 oacc;
  oacc[0] = 0.f; oacc[1] = 0.f; oacc[2] = 0.f; oacc[3] = 0.f;

  const uint4* __restrict__ kp = Kg + (size_t)bh * TT + lq;
  const int dcl = (lq < 7) ? lq : 6;  // clamp A-rows 7..15 to a real row
  const unsigned* __restrict__ vrow = Vtg + (size_t)bh * (7 * 512) + dcl * 512;
  unsigned* __restrict__ prow = &Ps[w][0];
  const int pwr = lq * 20;

  for (int kt2 = 0; kt2 < 32; ++kt2) {
    const uint4 ka = kp[kt2 * 32];        // tile 2*kt2   : keys 32*kt2+lq
    const uint4 kb = kp[kt2 * 32 + 16];   // tile 2*kt2+1
    const uint4 vv = *(const uint4*)(vrow + kt2 * 16 + lg * 4);

    f32x4 s0 = __builtin_amdgcn_mfma_f32_16x16x32_bf16(as_bf16x8(ka), qfrag,
                                                       cmb, 0, 0, 0);
    f32x4 s1 = __builtin_amdgcn_mfma_f32_16x16x32_bf16(as_bf16x8(kb), qfrag,
                                                       cmb, 0, 0, 0);
    // p = 2^(score - MBIAS); C layout: col=lq(query), rows = 4*lg+e (keys)
    const float p00 = __builtin_amdgcn_exp2f(s0[0]);
    const float p01 = __builtin_amdgcn_exp2f(s0[1]);
    const float p02 = __builtin_amdgcn_exp2f(s0[2]);
    const float p03 = __builtin_amdgcn_exp2f(s0[3]);
    const float p10 = __builtin_amdgcn_exp2f(s1[0]);
    const float p11 = __builtin_amdgcn_exp2f(s1[1]);
    const float p12 = __builtin_amdgcn_exp2f(s1[2]);
    const float p13 = __builtin_amdgcn_exp2f(s1[3]);
    // row lq: u32 idx 0..7 = tile0 keys 0..15, idx 8..15 = tile1 keys 16..31
    *(uint2*)(prow + pwr + 2 * lg) =
        make_uint2(cvt_pk_bf16(p00, p01), cvt_pk_bf16(p02, p03));
    *(uint2*)(prow + pwr + 8 + 2 * lg) =
        make_uint2(cvt_pk_bf16(p10, p11), cvt_pk_bf16(p12, p13));
    // B-frag: lane (q=lq, lg) takes k-offsets 8*lg..8*lg+7 = idx 4*lg..4*lg+3
    const uint4 pf = *(const uint4*)(prow + pwr + 4 * lg);
    oacc = __builtin_amdgcn_mfma_f32_16x16x32_bf16(as_bf16x8(vv),
                                                   as_bf16x8(pf), oacc, 0, 0, 0);
  }

  // ---- epilogue: O^T rows 0..5 = O, row 6 = l. Gather via Ps (reused).
  if (lg < 2) *(f32x4*)(prow + pwr + 4 * lg) = oacc;
  if (lane < 16) {
    const f32x4 o0 = *(const f32x4*)(prow + pwr);       // d0..d3
    const f32x4 o1 = *(const f32x4*)(prow + pwr + 4);   // d4,d5,l,junk
    const float inv = 1.0f / o1[2];
    float* __restrict__ dst =
        Om + ((size_t)(b * TT + q)) * DM + h * HD;
    *(float2*)(dst + 0) = make_float2(o0[0] * inv, o0[1] * inv);
    *(float2*)(dst + 2) = make_float2(o0[2] * inv, o0[3] * inv);
    *(float2*)(dst + 4) = make_float2(o1[0] * inv, o1[1] * inv);
  }
}

// ---------- kernel 3: output projection (proven R3-R5 pattern) ----------
__global__ __launch_bounds__(256, 4) void outproj_kernel(
    const float* __restrict__ O, const float* __restrict__ Wo,
    float* __restrict__ out) {
  __shared__ float wsh[DM * DM];
  for (int i = threadIdx.x; i < DM * DM; i += 256) wsh[i] = Wo[i];
  __syncthreads();
  const int rl = threadIdx.x >> 3, u = threadIdx.x & 7;
  const int r = blockIdx.x * 32 + rl;
  float x[DM];
  const float4* __restrict__ xr = (const float4*)(O + (size_t)r * DM);
#pragma unroll
  for (int i = 0; i < 6; ++i) {
    float4 t = xr[i];
    x[4 * i] = t.x; x[4 * i + 1] = t.y; x[4 * i + 2] = t.z; x[4 * i + 3] = t.w;
  }
#pragma unroll
  for (int jj = 0; jj < 3; ++jj) {
    const int j = u * 3 + jj;
    float a = 0.f;
#pragma unroll
    for (int c = 0; c < DM; ++c) a = fmaf(x[c], wsh[j * DM + c], a);
    out[(size_t)r * DM + j] = a;
  }
}

// ---------- launch ----------
extern "C" void kernel_launch(void* const* d_in, const int* in_sizes, int n_in,
                              void* d_out, int out_size, void* d_ws, size_t ws_size,
                              hipStream_t stream) {
  const float* X = (const float*)d_in[0];
  const float* Xen = (const float*)d_in[1];
  // d_in[2] = I_m : dead in the reference (masked_fill result discarded)
  const float* Wq = (const float*)d_in[3];
  const float* Wk = (const float*)d_in[4];
  const float* Wv = (const float*)d_in[5];
  const float* Wo = (const float*)d_in[6];

  char* ws = (char*)d_ws;
  float* Om = (float*)ws;                                  // 16384*24*4 = 1.57MB
  uint4* Kg = (uint4*)(ws + 2u * 1024 * 1024);             // 64*1024*16B = 1MB
  unsigned* Vtg = (unsigned*)(ws + 3u * 1024 * 1024 + 256 * 1024);  // 917KB

  kvproj_kernel<<<128, 256, 0, stream>>>(Xen, Wk, Wv, Kg, Vtg);
  attn_mfma_kernel<<<NB * NH * 16, 256, 0, stream>>>(X, Wq, Kg, Vtg, Om);
  outproj_kernel<<<NB * TT / 32, 256, 0, stream>>>(Om, Wo, (float*)d_out);
}

// Round 11
// 28.853 us; speedup vs baseline: 1.5304x; 1.1352x over previous
//
#include <hip/hip_runtime.h>
#include <hip/hip_bf16.h>

#define NB 16      // batch
#define TT 1024    // Tq == Tk
#define NH 4       // heads
#define HD 6       // head dim
#define DM 24      // model dim

// (1/sqrt(6)) * log2(e) -- folded into Q so scores are in exp2 domain
#define QSC 0.5889785f
// fixed conservative bias (log2 domain); softmax invariant; p <= 1, no overflow
#define MBIAS 32.0f

typedef float v2f __attribute__((ext_vector_type(2)));
typedef short bf16x8 __attribute__((ext_vector_type(8)));    // MFMA A/B frag
typedef float f32x16 __attribute__((ext_vector_type(16)));   // MFMA 32x32 C/D
typedef unsigned u32x2 __attribute__((ext_vector_type(2)));

__device__ __forceinline__ unsigned cvt_pk_bf16(float lo, float hi) {
  unsigned r;
  asm("v_cvt_pk_bf16_f32 %0, %1, %2" : "=v"(r) : "v"(lo), "v"(hi));
  return r;
}

__device__ __forceinline__ bf16x8 as_bf16x8(uint4 u) {
  union { uint4 u; bf16x8 b; } c;
  c.u = u;
  return c.b;
}

__device__ __forceinline__ unsigned short bf16of(float v) {
  union { __hip_bfloat16 b; unsigned short u; } c;
  c.b = __float2bfloat16(v);
  return c.u;
}

// packed dot of one 24-float row (6 float4, static-indexed) with a uniform
// weight row (SGPR via s_load -- proven R8 pattern).
__device__ __forceinline__ float dot24(const float4* r,
                                       const float* __restrict__ w) {
  v2f a = {0.f, 0.f};
#pragma unroll
  for (int i = 0; i < 6; ++i) {
    v2f xp, wp;
    xp.x = r[i].x; xp.y = r[i].y;
    wp.x = w[4 * i + 0]; wp.y = w[4 * i + 1];
    a = __builtin_elementwise_fma(xp, wp, a);
    xp.x = r[i].z; xp.y = r[i].w;
    wp.x = w[4 * i + 2]; wp.y = w[4 * i + 3];
    a = __builtin_elementwise_fma(xp, wp, a);
  }
  return a.x + a.y;
}

// ---------- kernel 1: K/V projection -> global bf16 MFMA images ----------
// Kg[bh][key] = 2x uint4: (k0..k5,0,0 | 0..0)  -- 32x32 A-row, 16 dims padded.
// Vt[bh][d][key] = bf16 (u16); d=0..5 = V^T, d=6 = ones (l via MFMA row 6).
// One thread per key. Projected once per bh.
__global__ __launch_bounds__(256, 4) void kvproj_kernel(
    const float* __restrict__ Xen, const float* __restrict__ Wk,
    const float* __restrict__ Wv, uint4* __restrict__ Kg,
    unsigned short* __restrict__ Vt) {
  const int gid = blockIdx.x * 256 + threadIdx.x;  // [0, 64*1024)
  const int bh = gid >> 10;
  const int key = gid & (TT - 1);
  const int b = bh >> 2, h = bh & 3;
  const float* __restrict__ wkh = Wk + h * HD * DM;
  const float* __restrict__ wvh = Wv + h * HD * DM;
  const float4* __restrict__ xa =
      (const float4*)(Xen + ((size_t)b * TT + key) * DM);
  float4 xr[6];
#pragma unroll
  for (int i = 0; i < 6; ++i) xr[i] = xa[i];
  float kk[HD], vv[HD];
#pragma unroll
  for (int d = 0; d < HD; ++d) {
    kk[d] = dot24(xr, wkh + d * DM);
    vv[d] = dot24(xr, wvh + d * DM);
  }
  uint4* __restrict__ kdst = Kg + ((size_t)bh * TT + key) * 2;
  kdst[0] = make_uint4(cvt_pk_bf16(kk[0], kk[1]), cvt_pk_bf16(kk[2], kk[3]),
                       cvt_pk_bf16(kk[4], kk[5]), 0u);
  kdst[1] = make_uint4(0u, 0u, 0u, 0u);
  unsigned short* __restrict__ vrow = Vt + (size_t)bh * (7 * TT);
#pragma unroll
  for (int d = 0; d < HD; ++d) vrow[d * TT + key] = bf16of(vv[d]);
  vrow[6 * TT + key] = 0x3F80u;  // 1.0 bf16
}

// ---------- kernel 2: MFMA 32x32 attention, zero-LDS ----------
// Per wave: 32 queries x 512 keys (ksplit=2). Per 32-key iteration:
//   S^T = mfma32(A=K-tile, B=Q-frag, C=-MBIAS)   (C: col=q, row=key_local)
//   p = exp2(S^T); cvt_pk pairs -> 8 u32; the C->B relayout is EXACTLY a
//   lane<->lane+32 exchange: permlane32_swap(c01,c45) -> (w0,w2),
//   (c23,c67) -> (w1,w3) [keys 0..15]; same for keys 16..31.
//   O^T += mfma32(A=V^T, B=P^T)  x2 (K=16 each); V^T row6=1 accumulates l.
// No LDS anywhere; partials (l,a0..a5) to P, combined by kernel 3 (R6-proven).
__global__ __launch_bounds__(256, 4) void attn_mfma32_kernel(
    const float* __restrict__ X, const float* __restrict__ Wq,
    const uint4* __restrict__ Kg, const unsigned short* __restrict__ Vt,
    float* __restrict__ P) {
  const int ks = blockIdx.x & 1;
  const int tile = (blockIdx.x >> 1) & 7;
  const int bh = blockIdx.x >> 4;
  const int b = bh >> 2, h = bh & 3;
  const int lane = threadIdx.x & 63;
  const int w = threadIdx.x >> 6;
  const int hi = lane >> 5;
  const int qc = lane & 31;
  const int q = tile * 128 + w * 32 + qc;

  // ---- Q projection -> B-frag (hi==0 lanes hold k=0..7 real; hi==1 zeros)
  const float* __restrict__ wqh = Wq + h * HD * DM;
  uint4 uq = make_uint4(0u, 0u, 0u, 0u);
  if (hi == 0) {
    const float4* __restrict__ xq =
        (const float4*)(X + ((size_t)b * TT + q) * DM);
    float4 xr[6];
#pragma unroll
    for (int i = 0; i < 6; ++i) xr[i] = xq[i];
    float qv[HD];
#pragma unroll
    for (int d = 0; d < HD; ++d) qv[d] = dot24(xr, wqh + d * DM) * QSC;
    uq = make_uint4(cvt_pk_bf16(qv[0], qv[1]), cvt_pk_bf16(qv[2], qv[3]),
                    cvt_pk_bf16(qv[4], qv[5]), 0u);
  }
  const bf16x8 qfrag = as_bf16x8(uq);

  f32x16 cmb, oacc;
#pragma unroll
  for (int i = 0; i < 16; ++i) { cmb[i] = -MBIAS; oacc[i] = 0.f; }

  // A-frag pointers. K: uint4 idx = (key)*2 + hi. V^T: d=clamp(qc), 8 keys/u4.
  const uint4* __restrict__ kp =
      Kg + (size_t)bh * (TT * 2) + (size_t)ks * TT + qc * 2 + hi;
  const int dcl = (qc < 7) ? qc : 6;
  const uint4* __restrict__ vp =
      (const uint4*)(Vt + (size_t)bh * (7 * TT) + dcl * TT) + ks * 64 + hi;

#pragma unroll 2
  for (int it = 0; it < 16; ++it) {
    const uint4 ka = kp[it * 64];
    const uint4 va = vp[it * 4];       // keys base+0..15  (this lane's 8)
    const uint4 vb = vp[it * 4 + 2];   // keys base+16..31

    f32x16 s = __builtin_amdgcn_mfma_f32_32x32x16_bf16(as_bf16x8(ka), qfrag,
                                                       cmb, 0, 0, 0);
    float p[16];
#pragma unroll
    for (int i = 0; i < 16; ++i) p[i] = __builtin_amdgcn_exp2f(s[i]);
    const unsigned c01 = cvt_pk_bf16(p[0], p[1]);
    const unsigned c23 = cvt_pk_bf16(p[2], p[3]);
    const unsigned c45 = cvt_pk_bf16(p[4], p[5]);
    const unsigned c67 = cvt_pk_bf16(p[6], p[7]);
    const unsigned c89 = cvt_pk_bf16(p[8], p[9]);
    const unsigned cAB = cvt_pk_bf16(p[10], p[11]);
    const unsigned cCD = cvt_pk_bf16(p[12], p[13]);
    const unsigned cEF = cvt_pk_bf16(p[14], p[15]);
    // lane<32: regs hold keys {0-3,8-11}+...; lane>=32: {4-7,12-15}.
    // swap gives each lane the partner words -> B-frag k=8*hi+{0..7}.
    const u32x2 r0 = __builtin_amdgcn_permlane32_swap(c01, c45, false, false);
    const u32x2 r1 = __builtin_amdgcn_permlane32_swap(c23, c67, false, false);
    const u32x2 r2 = __builtin_amdgcn_permlane32_swap(c89, cCD, false, false);
    const u32x2 r3 = __builtin_amdgcn_permlane32_swap(cAB, cEF, false, false);
    const uint4 pb0 = make_uint4(r0[0], r1[0], r0[1], r1[1]);
    const uint4 pb1 = make_uint4(r2[0], r3[0], r2[1], r3[1]);
    oacc = __builtin_amdgcn_mfma_f32_32x32x16_bf16(as_bf16x8(va),
                                                   as_bf16x8(pb0), oacc, 0, 0, 0);
    oacc = __builtin_amdgcn_mfma_f32_32x32x16_bf16(as_bf16x8(vb),
                                                   as_bf16x8(pb1), oacc, 0, 0, 0);
  }

  // ---- epilogue: C rows: hi=0 regs0-3 = d0..3; hi=1 regs0-2 = d4,d5,l
  const float a4 = __shfl_xor(oacc[0], 32);
  const float a5 = __shfl_xor(oacc[1], 32);
  const float ll = __shfl_xor(oacc[2], 32);
  if (hi == 0) {
    float* __restrict__ Pr =
        P + (((size_t)(bh * 2 + ks)) * TT + q) * 8;
    ((float4*)Pr)[0] = make_float4(ll, oacc[0], oacc[1], oacc[2]);
    ((float4*)Pr)[1] = make_float4(oacc[3], a4, a5, 0.f);
  }
}

// ---------- kernel 3: combine partials + output projection (R6-proven) -----
__global__ __launch_bounds__(256, 4) void combine_outproj_kernel(
    const float* __restrict__ P, const float* __restrict__ Wo,
    float* __restrict__ out) {
  __shared__ float wsh[DM * DM];
  __shared__ float o[32][25];
  for (int i = threadIdx.x; i < DM * DM; i += 256) wsh[i] = Wo[i];
  const int r0 = blockIdx.x * 32;
  {
    const int unit = threadIdx.x >> 1, e = threadIdx.x & 1;
    const int rl = unit >> 2, h = unit & 3;
    const int r = r0 + rl, b = r >> 10, t = r & (TT - 1);
    const int bh = b * NH + h;
    const float4* __restrict__ pp =
        (const float4*)(P + (((size_t)(bh * 2 + e)) * TT + t) * 8);
    float4 x0 = pp[0], x1 = pp[1];
    float l = x0.x, a0 = x0.y, a1 = x0.z, a2 = x0.w;
    float a3 = x1.x, a4 = x1.y, a5 = x1.z;
    l += __shfl_xor(l, 1);
    a0 += __shfl_xor(a0, 1);
    a1 += __shfl_xor(a1, 1);
    a2 += __shfl_xor(a2, 1);
    a3 += __shfl_xor(a3, 1);
    a4 += __shfl_xor(a4, 1);
    a5 += __shfl_xor(a5, 1);
    if (e == 0) {
      const float inv = 1.f / l;
      o[rl][h * HD + 0] = a0 * inv;
      o[rl][h * HD + 1] = a1 * inv;
      o[rl][h * HD + 2] = a2 * inv;
      o[rl][h * HD + 3] = a3 * inv;
      o[rl][h * HD + 4] = a4 * inv;
      o[rl][h * HD + 5] = a5 * inv;
    }
  }
  __syncthreads();
  const int rl = threadIdx.x >> 3, u = threadIdx.x & 7;
  const int r = r0 + rl;
  float x[DM];
#pragma unroll
  for (int c = 0; c < DM; ++c) x[c] = o[rl][c];
#pragma unroll
  for (int jj = 0; jj < 3; ++jj) {
    const int j = u * 3 + jj;
    float a = 0.f;
#pragma unroll
    for (int c = 0; c < DM; ++c) a = fmaf(x[c], wsh[j * DM + c], a);
    out[(size_t)r * DM + j] = a;
  }
}

// ---------- launch ----------
extern "C" void kernel_launch(void* const* d_in, const int* in_sizes, int n_in,
                              void* d_out, int out_size, void* d_ws, size_t ws_size,
                              hipStream_t stream) {
  const float* X = (const float*)d_in[0];
  const float* Xen = (const float*)d_in[1];
  // d_in[2] = I_m : dead in the reference (masked_fill result discarded)
  const float* Wq = (const float*)d_in[3];
  const float* Wk = (const float*)d_in[4];
  const float* Wv = (const float*)d_in[5];
  const float* Wo = (const float*)d_in[6];

  char* ws = (char*)d_ws;
  float* P = (float*)ws;                                   // 64*2*1024*8*4 = 4MB
  uint4* Kg = (uint4*)(ws + 4u * 1024 * 1024);             // 64*1024*32B = 2MB
  unsigned short* Vt =
      (unsigned short*)(ws + 6u * 1024 * 1024);            // 64*7*1024*2B = 896KB

  kvproj_kernel<<<NB * NH * TT / 256, 256, 0, stream>>>(Xen, Wk, Wv, Kg, Vt);
  attn_mfma32_kernel<<<NB * NH * 8 * 2, 256, 0, stream>>>(X, Wq, Kg, Vt, P);
  combine_outproj_kernel<<<NB * TT / 32, 256, 0, stream>>>(P, Wo,
                                                           (float*)d_out);
}